// Round 7
// baseline (268.250 us; speedup 1.0000x reference)
//
#include <hip/hip_runtime.h>
#include <hip/hip_cooperative_groups.h>
#include <math.h>

namespace cg = cooperative_groups;

#define EPS 1e-6f
#define C_CH 64          // channels (fixed by reference)
#define RPS  128         // blocks per segment (1024 total for B=8 -> 4/CU)

typedef float f32x4 __attribute__((ext_vector_type(4)));

// ---------------------------------------------------------------------------
// Single cooperative kernel: sumsq -> grid.sync -> finalize -> apply.
// 1024 blocks x 256 threads (4 blocks/CU, guaranteed co-resident).
// Thread t handles float4 (t&15) of rows (t>>4 + 16k); unroll-2.
// partial[(seg*RPS+bip)][64] in d_ws; finalize is redundant per-block
// (32 KB L2-hot read) to avoid a second grid sync.
// Apply uses nontemporal loads AND stores: three rounds of evidence say
// there is no exploitable L3 reuse here, so keep feat/out out of the way.
// ---------------------------------------------------------------------------
__global__ __launch_bounds__(256) void fused_kernel(
    const float4* __restrict__ feat,   // [N][16] float4 view of [N][64]
    const int*    __restrict__ offset, // [B] cumulative ends
    float*        __restrict__ partial,// [B*RPS][64]
    const float*  __restrict__ gamma,  // [64]
    const float4* __restrict__ beta4,  // [16]
    f32x4*        __restrict__ out)    // [N*16]
{
    cg::grid_group grid = cg::this_grid();

    const int seg   = blockIdx.x / RPS;
    const int bip   = blockIdx.x % RPS;
    const int start = (seg == 0) ? 0 : offset[seg - 1];
    const int end   = offset[seg];

    const int t    = threadIdx.x;
    const int c4   = t & 15;
    const int rsub = t >> 4;

    __shared__ float lds[16][C_CH];
    __shared__ float red[4][C_CH];
    __shared__ float mulsh[C_CH];

    // ---------------- phase 1: sum of squares ----------------
    {
        float4 a0 = make_float4(0.f, 0.f, 0.f, 0.f);
        float4 a1 = make_float4(0.f, 0.f, 0.f, 0.f);

        const int stride = RPS * 32;
        for (int row = start + bip * 32 + rsub; row < end; row += stride) {
            float4 v = feat[row * 16 + c4];
            a0.x = fmaf(v.x, v.x, a0.x);
            a0.y = fmaf(v.y, v.y, a0.y);
            a0.z = fmaf(v.z, v.z, a0.z);
            a0.w = fmaf(v.w, v.w, a0.w);
            int row2 = row + 16;
            if (row2 < end) {
                float4 w = feat[row2 * 16 + c4];
                a1.x = fmaf(w.x, w.x, a1.x);
                a1.y = fmaf(w.y, w.y, a1.y);
                a1.z = fmaf(w.z, w.z, a1.z);
                a1.w = fmaf(w.w, w.w, a1.w);
            }
        }
        a0.x += a1.x; a0.y += a1.y; a0.z += a1.z; a0.w += a1.w;

        lds[rsub][4 * c4 + 0] = a0.x;
        lds[rsub][4 * c4 + 1] = a0.y;
        lds[rsub][4 * c4 + 2] = a0.z;
        lds[rsub][4 * c4 + 3] = a0.w;
        __syncthreads();

        if (t < C_CH) {
            float s = 0.f;
            #pragma unroll
            for (int r = 0; r < 16; ++r) s += lds[r][t];
            partial[(seg * RPS + bip) * C_CH + t] = s;
        }
    }

    __threadfence();          // make partial writes device-visible
    grid.sync();

    // ---------------- phase 2: per-block finalize ----------------
    {
        const int c = t & 63;
        const int q = t >> 6;
        float s = 0.f;
        const float* p = partial + seg * RPS * C_CH + c;
        for (int b = q; b < RPS; b += 4) s += p[b * C_CH];
        red[q][c] = s;
        __syncthreads();
        if (t < C_CH) {
            float tot  = red[0][c] + red[1][c] + red[2][c] + red[3][c];
            float resp = sqrtf(tot);
            float m = resp;
            #pragma unroll
            for (int off = 1; off < 64; off <<= 1) m += __shfl_xor(m, off, 64);
            float mean = m * (1.0f / 64.0f);
            mulsh[c] = 1.0f + gamma[c] * (resp / (mean + EPS));
        }
        __syncthreads();
    }

    // ---------------- phase 3: apply ----------------
    {
        const float4 mm = ((const float4*)mulsh)[c4];
        const float4 bt = beta4[c4];
        const f32x4* featv = (const f32x4*)feat;

        const int stride = RPS * 32;
        for (int row = start + bip * 32 + rsub; row < end; row += stride) {
            f32x4 v = __builtin_nontemporal_load(&featv[row * 16 + c4]);
            f32x4 o;
            o.x = fmaf(v.x, mm.x, bt.x);
            o.y = fmaf(v.y, mm.y, bt.y);
            o.z = fmaf(v.z, mm.z, bt.z);
            o.w = fmaf(v.w, mm.w, bt.w);
            __builtin_nontemporal_store(o, &out[row * 16 + c4]);
            int row2 = row + 16;
            if (row2 < end) {
                f32x4 w = __builtin_nontemporal_load(&featv[row2 * 16 + c4]);
                f32x4 o2;
                o2.x = fmaf(w.x, mm.x, bt.x);
                o2.y = fmaf(w.y, mm.y, bt.y);
                o2.z = fmaf(w.z, mm.z, bt.z);
                o2.w = fmaf(w.w, mm.w, bt.w);
                __builtin_nontemporal_store(o2, &out[row2 * 16 + c4]);
            }
        }
    }
}

// ---------------------------------------------------------------------------
extern "C" void kernel_launch(void* const* d_in, const int* in_sizes, int n_in,
                              void* d_out, int out_size, void* d_ws, size_t ws_size,
                              hipStream_t stream)
{
    const float4* feat   = (const float4*)d_in[0];
    const int*    offset = (const int*)d_in[1];
    const float*  gamma  = (const float*)d_in[2];
    const float4* beta4  = (const float4*)d_in[3];
    f32x4*        out    = (f32x4*)d_out;

    const int B = in_sizes[1];       // number of segments (8)
    float* partial = (float*)d_ws;   // B*RPS*64 floats = 256 KB for B=8

    void* args[] = {
        (void*)&feat, (void*)&offset, (void*)&partial,
        (void*)&gamma, (void*)&beta4, (void*)&out
    };
    hipLaunchCooperativeKernel((void*)fused_kernel,
                               dim3(B * RPS), dim3(256),
                               args, 0, stream);
}

// Round 8
// 118.197 us; speedup vs baseline: 2.2695x; 2.2695x over previous
//
#include <hip/hip_runtime.h>
#include <math.h>

#define EPS 1e-6f
#define C_CH 64          // channels (fixed by reference)
#define BPS_A 256        // blocks per segment, reduction pass
#define BPS_C 256        // blocks per segment, apply pass

typedef float f32x4 __attribute__((ext_vector_type(4)));

// ---------------------------------------------------------------------------
// Pass A: per-block partial sum-of-squares per channel. Forward sweep,
// unroll-4 (4 float4 loads in flight). grid = B*BPS_A, block = 256.
// Thread t covers float4 (t&15) of rows ((t>>4) + 16k). Writes
// partial[blockIdx.x][64]. Deterministic, no atomics.
// ---------------------------------------------------------------------------
__global__ __launch_bounds__(256) void sumsq_partial(
    const float4* __restrict__ feat,   // [N][16] float4 view of [N][64] f32
    const int* __restrict__ offset,    // [B] cumulative (exclusive end)
    float* __restrict__ partial)       // [B*BPS_A][64]
{
    const int seg  = blockIdx.x / BPS_A;
    const int bip  = blockIdx.x - seg * BPS_A;
    const int start = (seg == 0) ? 0 : offset[seg - 1];
    const int end   = offset[seg];

    const int t    = threadIdx.x;
    const int c4   = t & 15;
    const int rsub = t >> 4;

    float4 a0 = make_float4(0.f, 0.f, 0.f, 0.f);
    float4 a1 = make_float4(0.f, 0.f, 0.f, 0.f);
    float4 a2 = make_float4(0.f, 0.f, 0.f, 0.f);
    float4 a3 = make_float4(0.f, 0.f, 0.f, 0.f);

    const int stride = BPS_A * 64;      // 4 chunks of 16 rows per iter
    for (int row = start + bip * 64 + rsub; row < end; row += stride) {
        int r1 = row + 16, r2 = row + 32, r3 = row + 48;
        float4 v0 = feat[row * 16 + c4];
        if (r1 < end) {
            float4 v1 = feat[r1 * 16 + c4];
            a1.x = fmaf(v1.x, v1.x, a1.x);
            a1.y = fmaf(v1.y, v1.y, a1.y);
            a1.z = fmaf(v1.z, v1.z, a1.z);
            a1.w = fmaf(v1.w, v1.w, a1.w);
        }
        if (r2 < end) {
            float4 v2 = feat[r2 * 16 + c4];
            a2.x = fmaf(v2.x, v2.x, a2.x);
            a2.y = fmaf(v2.y, v2.y, a2.y);
            a2.z = fmaf(v2.z, v2.z, a2.z);
            a2.w = fmaf(v2.w, v2.w, a2.w);
        }
        if (r3 < end) {
            float4 v3 = feat[r3 * 16 + c4];
            a3.x = fmaf(v3.x, v3.x, a3.x);
            a3.y = fmaf(v3.y, v3.y, a3.y);
            a3.z = fmaf(v3.z, v3.z, a3.z);
            a3.w = fmaf(v3.w, v3.w, a3.w);
        }
        a0.x = fmaf(v0.x, v0.x, a0.x);
        a0.y = fmaf(v0.y, v0.y, a0.y);
        a0.z = fmaf(v0.z, v0.z, a0.z);
        a0.w = fmaf(v0.w, v0.w, a0.w);
    }
    a0.x += a1.x + a2.x + a3.x;
    a0.y += a1.y + a2.y + a3.y;
    a0.z += a1.z + a2.z + a3.z;
    a0.w += a1.w + a2.w + a3.w;

    __shared__ float lds[16][C_CH];
    lds[rsub][4 * c4 + 0] = a0.x;
    lds[rsub][4 * c4 + 1] = a0.y;
    lds[rsub][4 * c4 + 2] = a0.z;
    lds[rsub][4 * c4 + 3] = a0.w;
    __syncthreads();

    if (t < C_CH) {
        float s = 0.f;
        #pragma unroll
        for (int r = 0; r < 16; ++r) s += lds[r][t];
        partial[blockIdx.x * C_CH + t] = s;
    }
}

// ---------------------------------------------------------------------------
// Pass C (fused finalize + apply):
// Prelude: coalesced float4 re-reduce of the segment's BPS_A partial rows
// (16 iterations of full-row loads + LDS tree; L2-hot) -> response ->
// channel mean -> mul[c] in LDS.
// Main: out = feat*mul + beta, float4 unroll-4, NONTEMPORAL stores
// (normal loads — R7 proved nt loads are disastrous).
// grid = B*BPS_C, block = 256.
// ---------------------------------------------------------------------------
__global__ __launch_bounds__(256) void apply_kernel(
    const float4* __restrict__ feat,
    const int* __restrict__ offset,
    const float4* __restrict__ partial4, // [B*BPS_A][16] float4 view
    const float* __restrict__ gamma,     // [64]
    const float4* __restrict__ beta4,    // [16]
    f32x4* __restrict__ out)
{
    const int seg = blockIdx.x / BPS_C;
    const int bip = blockIdx.x - seg * BPS_C;
    const int start = (seg == 0) ? 0 : offset[seg - 1];
    const int end   = offset[seg];

    const int t    = threadIdx.x;
    const int c4   = t & 15;
    const int rsub = t >> 4;

    __shared__ float lds[16][C_CH];
    __shared__ float mulsh[C_CH];

    // --- prelude: coalesced per-block finalize ---
    {
        float4 acc = make_float4(0.f, 0.f, 0.f, 0.f);
        const float4* base = partial4 + (seg * BPS_A) * 16;
        #pragma unroll
        for (int r0 = 0; r0 < BPS_A; r0 += 16) {
            float4 v = base[(r0 + rsub) * 16 + c4];
            acc.x += v.x; acc.y += v.y; acc.z += v.z; acc.w += v.w;
        }
        lds[rsub][4 * c4 + 0] = acc.x;
        lds[rsub][4 * c4 + 1] = acc.y;
        lds[rsub][4 * c4 + 2] = acc.z;
        lds[rsub][4 * c4 + 3] = acc.w;
        __syncthreads();

        if (t < C_CH) {
            float s = 0.f;
            #pragma unroll
            for (int r = 0; r < 16; ++r) s += lds[r][t];
            float resp = sqrtf(s);
            float m = resp;
            #pragma unroll
            for (int off = 1; off < 64; off <<= 1) m += __shfl_xor(m, off, 64);
            float mean = m * (1.0f / 64.0f);
            mulsh[t] = 1.0f + gamma[t] * (resp / (mean + EPS));
        }
        __syncthreads();
    }

    const float4 mm = ((const float4*)mulsh)[c4];
    const float4 bt = beta4[c4];

    const int stride = BPS_C * 64;
    for (int row = start + bip * 64 + rsub; row < end; row += stride) {
        int r1 = row + 16, r2 = row + 32, r3 = row + 48;
        float4 v0 = feat[row * 16 + c4];
        f32x4 o0;
        o0.x = fmaf(v0.x, mm.x, bt.x);
        o0.y = fmaf(v0.y, mm.y, bt.y);
        o0.z = fmaf(v0.z, mm.z, bt.z);
        o0.w = fmaf(v0.w, mm.w, bt.w);
        __builtin_nontemporal_store(o0, &out[row * 16 + c4]);
        if (r1 < end) {
            float4 v1 = feat[r1 * 16 + c4];
            f32x4 o1;
            o1.x = fmaf(v1.x, mm.x, bt.x);
            o1.y = fmaf(v1.y, mm.y, bt.y);
            o1.z = fmaf(v1.z, mm.z, bt.z);
            o1.w = fmaf(v1.w, mm.w, bt.w);
            __builtin_nontemporal_store(o1, &out[r1 * 16 + c4]);
        }
        if (r2 < end) {
            float4 v2 = feat[r2 * 16 + c4];
            f32x4 o2;
            o2.x = fmaf(v2.x, mm.x, bt.x);
            o2.y = fmaf(v2.y, mm.y, bt.y);
            o2.z = fmaf(v2.z, mm.z, bt.z);
            o2.w = fmaf(v2.w, mm.w, bt.w);
            __builtin_nontemporal_store(o2, &out[r2 * 16 + c4]);
        }
        if (r3 < end) {
            float4 v3 = feat[r3 * 16 + c4];
            f32x4 o3;
            o3.x = fmaf(v3.x, mm.x, bt.x);
            o3.y = fmaf(v3.y, mm.y, bt.y);
            o3.z = fmaf(v3.z, mm.z, bt.z);
            o3.w = fmaf(v3.w, mm.w, bt.w);
            __builtin_nontemporal_store(o3, &out[r3 * 16 + c4]);
        }
    }
}

// ---------------------------------------------------------------------------
extern "C" void kernel_launch(void* const* d_in, const int* in_sizes, int n_in,
                              void* d_out, int out_size, void* d_ws, size_t ws_size,
                              hipStream_t stream)
{
    const float4* feat   = (const float4*)d_in[0];
    const int*    offset = (const int*)d_in[1];
    const float*  gamma  = (const float*)d_in[2];
    const float4* beta4  = (const float4*)d_in[3];
    f32x4*        out    = (f32x4*)d_out;

    const int B = in_sizes[1];       // number of segments (8)
    float* partial = (float*)d_ws;   // B*BPS_A*64 floats = 512 KB for B=8

    sumsq_partial<<<B * BPS_A, 256, 0, stream>>>(feat, offset, partial);
    apply_kernel<<<B * BPS_C, 256, 0, stream>>>(feat, offset,
                                                (const float4*)partial,
                                                gamma, beta4, out);
}